// Round 1
// baseline (236.467 us; speedup 1.0000x reference)
//
#include <hip/hip_runtime.h>

// VQ-VAE VectorQuantizer forward, fp32.
// inputs:  d_in[0] = x (64,64,32,32) NCHW fp32; d_in[1] = embedding (512,64) fp32
// outputs (concat fp32): [loss(1) | quantized_st NCHW (4194304) | perplexity(1) | quantized_st NHWC-flat (4194304)]

constexpr int DIM    = 64;
constexpr int KC     = 512;
constexpr int HW     = 1024;          // 32*32
constexpr int NPTS   = 65536;         // 64*1024
constexpr int QELEMS = NPTS * DIM;    // 4194304

// ws layout: [0..4) float loss accum; [64..2112) int hist[512]; [4096..266240) int idx[65536]

__global__ __launch_bounds__(256, 1)
void vq_argmin_kernel(const float* __restrict__ x, const float* __restrict__ emb,
                      int* __restrict__ idx, int* __restrict__ hist,
                      float* __restrict__ loss_accum)
{
    __shared__ float se[KC * DIM];   // 128 KB codebook
    __shared__ float sn[KC];         // ||e_k||^2
    __shared__ int   shist[KC];

    const int tid = threadIdx.x;

    // stage codebook, coalesced float4
    const float4* esrc = reinterpret_cast<const float4*>(emb);
    float4* edst = reinterpret_cast<float4*>(se);
    #pragma unroll
    for (int i = 0; i < (KC * DIM / 4) / 256; ++i)
        edst[tid + i * 256] = esrc[tid + i * 256];
    for (int i = tid; i < KC; i += 256) shist[i] = 0;
    __syncthreads();

    // code norms (2 per thread)
    for (int k = tid; k < KC; k += 256) {
        float s = 0.f;
        #pragma unroll
        for (int d = 0; d < DIM; ++d) { float v = se[k * DIM + d]; s = fmaf(v, v, s); }
        sn[k] = s;
    }
    __syncthreads();

    // one point per thread; lanes <-> consecutive hw -> coalesced strided x reads
    const int n  = blockIdx.x * 256 + tid;
    const int b  = n >> 10;
    const int hw = n & (HW - 1);
    const float* xp = x + (size_t)b * DIM * HW + hw;
    float xr[DIM];
    #pragma unroll
    for (int d = 0; d < DIM; ++d) xr[d] = xp[(size_t)d * HW];

    // argmin_k ( ||e_k||^2 - 2 x.e_k )   (the ||x||^2 shift is order-preserving)
    float best = 3.4e38f;
    int bestk = 0;
    for (int k = 0; k < KC; ++k) {
        const float* ek = se + k * DIM;
        float a0 = 0.f, a1 = 0.f, a2 = 0.f, a3 = 0.f;   // ILP-4 to cover FMA latency
        #pragma unroll
        for (int d = 0; d < DIM; d += 4) {
            a0 = fmaf(xr[d + 0], ek[d + 0], a0);
            a1 = fmaf(xr[d + 1], ek[d + 1], a1);
            a2 = fmaf(xr[d + 2], ek[d + 2], a2);
            a3 = fmaf(xr[d + 3], ek[d + 3], a3);
        }
        float dist = sn[k] - 2.f * ((a0 + a1) + (a2 + a3));
        if (dist < best) { best = dist; bestk = k; }
    }
    idx[n] = bestk;
    atomicAdd(&shist[bestk], 1);

    // loss partial: sum_d (e_best[d] - x[d])^2
    float lsum = 0.f;
    const float* ebest = se + bestk * DIM;
    #pragma unroll
    for (int d = 0; d < DIM; ++d) {
        float diff = ebest[d] - xr[d];
        lsum = fmaf(diff, diff, lsum);
    }
    #pragma unroll
    for (int off = 32; off > 0; off >>= 1)
        lsum += __shfl_down(lsum, off, 64);
    if ((tid & 63) == 0) atomicAdd(loss_accum, lsum);

    __syncthreads();
    for (int i = tid; i < KC; i += 256) {
        int c = shist[i];
        if (c) atomicAdd(&hist[i], c);
    }
}

__global__ __launch_bounds__(256)
void vq_outputs_kernel(const float* __restrict__ emb, const int* __restrict__ idx,
                       float* __restrict__ out_nchw, float* __restrict__ out_flat)
{
    const int i = blockIdx.x * 256 + threadIdx.x;
    if (i < QELEMS) {
        // NCHW: i = ((b*64 + d) * 1024 + hw)
        const int d  = (i >> 10) & 63;
        const int b  = i >> 16;
        const int hw = i & 1023;
        const int n  = (b << 10) | hw;
        out_nchw[i] = emb[idx[n] * DIM + d];     // coalesced idx read, L2-resident emb gather
    } else {
        const int j = i - QELEMS;
        // NHWC flat: j = n*64 + d ; one n per wave -> broadcast idx, coalesced emb row read
        const int n = j >> 6;
        const int d = j & 63;
        out_flat[j] = emb[idx[n] * DIM + d];
    }
}

__global__ __launch_bounds__(512, 1)
void vq_finalize_kernel(const int* __restrict__ hist, const float* __restrict__ loss_accum,
                        float* __restrict__ out_loss, float* __restrict__ out_perp)
{
    __shared__ float wsum[8];
    const int tid = threadIdx.x;
    const float p = (float)hist[tid] * (1.0f / (float)NPTS);
    float t = p * logf(p + 1e-10f);
    #pragma unroll
    for (int off = 32; off > 0; off >>= 1)
        t += __shfl_down(t, off, 64);
    if ((tid & 63) == 0) wsum[tid >> 6] = t;
    __syncthreads();
    if (tid == 0) {
        float s = 0.f;
        #pragma unroll
        for (int w = 0; w < 8; ++w) s += wsum[w];
        *out_perp = expf(-s);
        // loss = q_latent + 0.25*e_latent, both == mean((q-x)^2) in fwd
        *out_loss = (*loss_accum) * 1.25f / (float)QELEMS;
    }
}

extern "C" void kernel_launch(void* const* d_in, const int* in_sizes, int n_in,
                              void* d_out, int out_size, void* d_ws, size_t ws_size,
                              hipStream_t stream)
{
    const float* x   = (const float*)d_in[0];
    const float* emb = (const float*)d_in[1];
    float* out = (float*)d_out;

    float* loss_accum = (float*)d_ws;
    int*   hist       = (int*)((char*)d_ws + 64);
    int*   idx        = (int*)((char*)d_ws + 4096);

    // zero loss accumulator + histogram (ws is poisoned 0xAA before every launch)
    hipMemsetAsync(d_ws, 0, 4096, stream);

    vq_argmin_kernel<<<NPTS / 256, 256, 0, stream>>>(x, emb, idx, hist, loss_accum);

    // out[0]=loss | out[1..]=NCHW | out[1+Q]=perplexity | out[2+Q..]=NHWC flat
    vq_outputs_kernel<<<(2 * QELEMS) / 256, 256, 0, stream>>>(
        emb, idx, out + 1, out + 2 + QELEMS);

    vq_finalize_kernel<<<1, 512, 0, stream>>>(hist, loss_accum, out, out + 1 + QELEMS);
}